// Round 10
// baseline (235.850 us; speedup 1.0000x reference)
//
#include <hip/hip_runtime.h>
#include <hip/hip_bf16.h>

#define NN 100000   // nodes
#define NE 1600000  // edges
#define NG 1000     // graphs
#define NBK 196     // dst buckets of 512 nodes (196*512 >= NN)
#define BSH 9       // bucket shift
#define SLOT 10240  // tmp slack region per bucket (mean 8192 + padding)
#define SLOTC 12288 // csr slack region per bucket (mean 8192 + 8-align pad ~3.5/node)
#define GAGG 2048   // persistent agg grid: 8 blocks/CU x 256 CUs

typedef short short8 __attribute__((ext_vector_type(8)));
typedef float f32x4 __attribute__((ext_vector_type(4)));
typedef float f32x2 __attribute__((ext_vector_type(2)));

static inline int cdiv(int a, int b) { return (a + b - 1) / b; }

// f32 -> bf16 (RNE) and helpers
__device__ __forceinline__ unsigned short f2b(float f) {
    unsigned int u = __float_as_uint(f);
    u += 0x7fff + ((u >> 16) & 1);
    return (unsigned short)(u >> 16);
}
__device__ __forceinline__ unsigned int pack2(float lo, float hi) {
    return (unsigned int)f2b(lo) | ((unsigned int)f2b(hi) << 16);
}

// fp8 e4m3 (OCP) hardware converts; word select must be an immediate constant
template <int W>
__device__ __forceinline__ f32x2 f8_2f(unsigned int v) {
    return __builtin_amdgcn_cvt_pk_f32_fp8((int)v, W);
}
__device__ __forceinline__ unsigned int f2f8_lo(float a, float b, unsigned int old) {
    return (unsigned int)__builtin_amdgcn_cvt_pk_fp8_f32(a, b, (int)old, false);
}
__device__ __forceinline__ unsigned int f2f8_hi(float a, float b, unsigned int old) {
    return (unsigned int)__builtin_amdgcn_cvt_pk_fp8_f32(a, b, (int)old, true);
}
__device__ __forceinline__ unsigned char f2f8s(float a) {
    return (unsigned char)(__builtin_amdgcn_cvt_pk_fp8_f32(a, a, 0, false) & 0xFF);
}

// ------------------------------------------------- prep
// Permuted byte order for fp8 rows: byte q holds col c(q) = (q&7)*16 + (q>>3).
// Wt1: bf16 [n][k] for layer-1 bf16 MFMA.
// Wt2p: fp8 [n][q] with k-rows permuted by the SAME c(q) as A1's byte order —
// joint k-permutation of A and B leaves the dot product invariant.
// Block 128 also zeroes row NN of BOTH gather buffers (dummy pad target).
// Blocks 129..519: scan sorted batch[] for graph start offsets.
// Blocks 520..644: zero gsum (per-graph f32 pool accumulators).
__global__ __launch_bounds__(256) void k_prep(const float* __restrict__ W1,
                                              const float* __restrict__ W2,
                                              const float* __restrict__ b1,
                                              const float* __restrict__ b2,
                                              unsigned short* __restrict__ Wt1,
                                              unsigned char* __restrict__ Wt2p,
                                              float* __restrict__ b1p,
                                              float* __restrict__ b2p,
                                              int* __restrict__ gcur,
                                              const int* __restrict__ batch,
                                              int* __restrict__ gstart,
                                              unsigned char* __restrict__ Hs8,
                                              unsigned char* __restrict__ Hg2,
                                              float* __restrict__ gsum) {
    int b = blockIdx.x, t = threadIdx.x;
    if (b < 128) {
        if (t < 128) {
            Wt1[b * 128 + t] = f2b(W1[t * 128 + b]);
        } else {
            int q = t - 128;
            int c = (q & 7) * 16 + (q >> 3);
            Wt2p[b * 128 + q] = f2f8s(W2[c * 128 + b]);
        }
    } else if (b == 128) {
        if (t < NBK) gcur[t] = t * SLOT;
        if (t < 128) {
            int c = (t & 7) * 16 + (t >> 3);  // col held at permuted position t
            b1p[t] = b1[c];
            b2p[t] = b2[c];
        }
        if (t >= 128 && t < 136) {
            uint4 z; z.x = 0u; z.y = 0u; z.z = 0u; z.w = 0u;
            ((uint4*)(Hs8 + (size_t)NN * 128))[t - 128] = z;  // zero dummy row L1
        }
        if (t >= 136 && t < 144) {
            uint4 z; z.x = 0u; z.y = 0u; z.z = 0u; z.w = 0u;
            ((uint4*)(Hg2 + (size_t)NN * 128))[t - 136] = z;  // zero dummy row L2
        }
    } else if (b < 520) {
        // graph boundary scan: n in [0, NN]; virtual batch[NN] = NG
        int n = (b - 129) * 256 + t;
        if (n <= NN) {
            int cur = (n == NN) ? NG : batch[n];
            int prev = (n == 0) ? -1 : batch[n - 1];
            for (int g = prev + 1; g <= cur; g++) gstart[g] = n;
        }
    } else {
        // zero gsum: NG*128 floats = 32000 uint4, 125 blocks x 256 threads
        int i = (b - 520) * 256 + t;
        if (i < NG * 32) {
            uint4 z; z.x = 0u; z.y = 0u; z.z = 0u; z.w = 0u;
            ((uint4*)gsum)[i] = z;
        }
    }
}

// -------------------------------------------------------- two-phase binning
// LDS counting-sort (R17-verified): entries sorted into bucket order in LDS,
// then written out linearly (coalesced).
__global__ __launch_bounds__(256) void k_bin2(const int* __restrict__ row,
                                              const int* __restrict__ col,
                                              int* __restrict__ gcur,
                                              unsigned int* __restrict__ tmp) {
    __shared__ unsigned int ent[4000];
    __shared__ unsigned int srt[4000];
    __shared__ unsigned char bkt[4000];
    __shared__ unsigned char bky[4000];
    __shared__ int cnt[NBK];
    __shared__ int gbase[NBK];
    __shared__ int lbase[NBK];
    __shared__ int sh[256];
    int t = threadIdx.x;
    if (t < NBK) cnt[t] = 0;
    __syncthreads();
    const int q0 = blockIdx.x * 1000;  // int4 index base (4000 edges)
    const int4* col4 = (const int4*)col;
    const int4* row4 = (const int4*)row;
#pragma unroll
    for (int it = 0; it < 4; it++) {
        int idx = it * 256 + t;
        if (idx < 1000) {
            int4 c = col4[q0 + idx];
            int4 r = row4[q0 + idx];
            int d, b;
            d = c.x; b = d >> BSH; atomicAdd(&cnt[b], 1);
            ent[idx * 4 + 0] = ((unsigned int)(d & 511) << 17) | (unsigned int)r.x;
            bkt[idx * 4 + 0] = (unsigned char)b;
            d = c.y; b = d >> BSH; atomicAdd(&cnt[b], 1);
            ent[idx * 4 + 1] = ((unsigned int)(d & 511) << 17) | (unsigned int)r.y;
            bkt[idx * 4 + 1] = (unsigned char)b;
            d = c.z; b = d >> BSH; atomicAdd(&cnt[b], 1);
            ent[idx * 4 + 2] = ((unsigned int)(d & 511) << 17) | (unsigned int)r.z;
            bkt[idx * 4 + 2] = (unsigned char)b;
            d = c.w; b = d >> BSH; atomicAdd(&cnt[b], 1);
            ent[idx * 4 + 3] = ((unsigned int)(d & 511) << 17) | (unsigned int)r.w;
            bkt[idx * 4 + 3] = (unsigned char)b;
        }
    }
    __syncthreads();
    int v = (t < NBK) ? cnt[t] : 0;
    sh[t] = v;
    __syncthreads();
    for (int d = 1; d < 256; d <<= 1) {
        int u = (t >= d) ? sh[t - d] : 0;
        __syncthreads();
        sh[t] += u;
        __syncthreads();
    }
    if (t < NBK) {
        lbase[t] = sh[t] - v;
        gbase[t] = atomicAdd(&gcur[t], v);
        cnt[t] = sh[t] - v;  // becomes local cursor
    }
    __syncthreads();
#pragma unroll
    for (int it = 0; it < 16; it++) {
        int i = it * 256 + t;
        if (i < 4000) {
            int b = bkt[i];
            int p = atomicAdd(&cnt[b], 1);
            srt[p] = ent[i];
            bky[p] = (unsigned char)b;
        }
    }
    __syncthreads();
#pragma unroll
    for (int it = 0; it < 16; it++) {
        int i = it * 256 + t;
        if (i < 4000) {
            int b = bky[i];
            tmp[gbase[b] + (i - lbase[b])] = srt[i];
        }
    }
}

// -------------------------------------------------------- per-bucket CSR
// Segments padded to 8-entry alignment; pad entries filled with dummy index NN
// (points at the zeroed row of the gather buffer) so aggregation gathers
// unconditionally. meta[node] = csr_offset | (padded_degree << 22).
// Entries stashed in LDS during the count pass (no tmp re-read).
__global__ __launch_bounds__(1024) void k_bucket(const unsigned int* __restrict__ tmp,
                                                 const int* __restrict__ gcur,
                                                 unsigned int* __restrict__ meta,
                                                 float* __restrict__ dinv,
                                                 int* __restrict__ csr_src) {
    __shared__ unsigned int sent[SLOT];  // 40 KB entry stash
    __shared__ int cnt[512];
    __shared__ int loff[512];
    __shared__ int send[512];
    __shared__ int sh[256];
    int b = blockIdx.x, t = threadIdx.x;
    int j0 = b << BSH;
    int nd = min(512, NN - j0);
    int rb = b * SLOT;     // tmp base
    int rbc = b * SLOTC;   // csr base
    int m = gcur[b] - rb;
    if (t < 512) cnt[t] = 0;
    __syncthreads();
    for (int i = t; i < m; i += 1024) {
        unsigned int e = tmp[rb + i];
        sent[i] = e;
        atomicAdd(&cnt[e >> 17], 1);
    }
    __syncthreads();
    int r0 = 0, r1 = 0, p0 = 0, ts = 0;
    if (t < 256) {
        r0 = cnt[2 * t]; r1 = cnt[2 * t + 1];
        p0 = (r0 + 7) & ~7;
        int p1 = (r1 + 7) & ~7;  // pad to 8-entry alignment
        ts = p0 + p1;
        sh[t] = ts;
    }
    __syncthreads();
    for (int d = 1; d < 256; d <<= 1) {
        int u = (t >= d && t < 256) ? sh[t - d] : 0;
        __syncthreads();
        if (t < 256) sh[t] += u;
        __syncthreads();
    }
    if (t < 256) {
        int ex = sh[t] - ts;
        loff[2 * t] = ex;
        loff[2 * t + 1] = ex + p0;
    }
    __syncthreads();
    for (int j = t; j < nd; j += 1024) {
        int o = rbc + loff[j];
        int dg = cnt[j];
        int dgp = (dg + 7) & ~7;
        meta[j0 + j] = (unsigned int)o | ((unsigned int)dgp << 22);
        send[j] = o + dgp;
        dinv[j0 + j] = rsqrtf((float)(dg + 1));  // +1 self-loop
        cnt[j] = o;  // becomes cursor
    }
    __syncthreads();
    for (int i = t; i < m; i += 1024) {
        unsigned int e = sent[i];
        int d = e >> 17;
        int s = (int)(e & 0x1FFFFu);
        int p = atomicAdd(&cnt[d], 1);
        csr_src[p] = s;
    }
    __syncthreads();
    for (int j = t; j < nd; j += 1024) {
        int pe = send[j];
        for (int p = cnt[j]; p < pe; p++) csr_src[p] = NN;  // dummy (zero row)
    }
}

// ---------------------------------------------------------------- GEMM layer 1
// Hs8[r] = fp8( dinv[r] * (bf16(x) @ Wt1^T) row r ), PERMUTED bytes (q=n16*8+ct).
__global__ __launch_bounds__(256) void k_gemm1(const float* __restrict__ X,
                                               const unsigned short* __restrict__ Wt,
                                               const float* __restrict__ dinv,
                                               unsigned char* __restrict__ Hs8) {
    __shared__ __align__(16) unsigned short Ws[128 * 128];  // 32 KB
    int t = threadIdx.x;
#pragma unroll
    for (int i = 0; i < 8; i++) {
        int id = t + i * 256;
        int n = id >> 4, c = id & 15;
        *(short8*)((char*)Ws + n * 256 + ((c ^ (n & 15)) << 4)) =
            *(const short8*)(Wt + n * 128 + c * 8);
    }
    __syncthreads();

    int lane = t & 63, wid = t >> 6;
    int n16 = lane & 15, quad = lane >> 4;
    int row_base = blockIdx.x * 128 + wid * 32;

    short8 a[2][4];
#pragma unroll
    for (int rt = 0; rt < 2; rt++) {
        int r = row_base + rt * 16 + n16;
        if (r > NN - 1) r = NN - 1;
        const float* ap = X + (size_t)r * 128 + quad * 8;
#pragma unroll
        for (int ks = 0; ks < 4; ks++) {
            float4 v0 = *(const float4*)(ap + ks * 32);
            float4 v1 = *(const float4*)(ap + ks * 32 + 4);
            uint4 up;
            up.x = pack2(v0.x, v0.y); up.y = pack2(v0.z, v0.w);
            up.z = pack2(v1.x, v1.y); up.w = pack2(v1.z, v1.w);
            a[rt][ks] = *(short8*)&up;
        }
    }

    f32x4 acc[2][8];
#pragma unroll
    for (int rt = 0; rt < 2; rt++)
#pragma unroll
        for (int ct = 0; ct < 8; ct++)
            acc[rt][ct] = (f32x4){0.f, 0.f, 0.f, 0.f};

#pragma unroll
    for (int ks = 0; ks < 4; ks++) {
#pragma unroll
        for (int ct = 0; ct < 8; ct++) {
            short8 b = *(const short8*)((const char*)Ws +
                        (ct * 16 + n16) * 256 + ((((ks << 2) + quad) ^ n16) << 4));
            acc[0][ct] = __builtin_amdgcn_mfma_f32_16x16x32_bf16(a[0][ks], b, acc[0][ct], 0, 0, 0);
            acc[1][ct] = __builtin_amdgcn_mfma_f32_16x16x32_bf16(a[1][ks], b, acc[1][ct], 0, 0, 0);
        }
    }

#pragma unroll
    for (int rt = 0; rt < 2; rt++) {
#pragma unroll
        for (int reg = 0; reg < 4; reg++) {
            int row = row_base + rt * 16 + quad * 4 + reg;
            if (row < NN) {
                float di = dinv[row];
                unsigned int u0 = 0, u1 = 0;
                u0 = f2f8_lo(acc[rt][0][reg] * di, acc[rt][1][reg] * di, u0);
                u0 = f2f8_hi(acc[rt][2][reg] * di, acc[rt][3][reg] * di, u0);
                u1 = f2f8_lo(acc[rt][4][reg] * di, acc[rt][5][reg] * di, u1);
                u1 = f2f8_hi(acc[rt][6][reg] * di, acc[rt][7][reg] * di, u1);
                uint2 o; o.x = u0; o.y = u1;
                ((uint2*)(Hs8 + (size_t)row * 128))[n16] = o;
            }
        }
    }
}

// ------------------------------------------- aggregation (+fused tails)
// out[i] = relu( dinv[i] * (Hs[i] + sum_e Hs[src_e]) + bias ), fp8 permuted.
// PERSISTENT grid-stride version: GAGG blocks (8/CU exact) each loop over
// ~3 node-tiles — steady resident occupancy, no dispatch churn; W2 staging
// amortized per block. Inner gather identical to the R4/R8-verified shape
// (16 lanes/node, 16 edges/iter, 16 gathers in flight, index prefetch; CSR
// 8-padded with dummy index NN so the lower 8 gathers are unconditional).
// Per-tile LDS tiles are PARITY DOUBLE-BUFFERED: with one barrier per tile,
// a fast wave's iter-k+1 LDS write would race slow waves' iter-k reads; a
// thread enters iter k+2 only after barrier(k+1), which happens-after all
// iter-k consumers — so 2 buffers suffice.
// MODE=1 (layer 1): W2 in 16KB LDS (staged once); A-tile 2x2KB dbuf; after
// the barrier, WAVES 0 AND 1 run the fp8 MFMA (wave w: column-tiles
// w*4..w*4+3). Byte position within each 8B chunk == ct, so wave0's 4 results
// form the low dword and wave1's the high dword -> direct dword stores.
// MODE=2 (layer 2 + fused mean-pool): post-relu f32 -> [16][132] LDS tile
// (2x8512B dbuf); threads 0..127 run a graph-segmented column reduce over the
// tile's 16 consecutive nodes and atomicAdd partials into gsum[NG][128].
template <int MODE>
__global__ __launch_bounds__(256) void k_agg(const unsigned char* __restrict__ Hb,
                                             const unsigned int* __restrict__ meta,
                                             const int* __restrict__ csr_src,
                                             const float* __restrict__ dinv,
                                             const float* __restrict__ biasp,
                                             const unsigned char* __restrict__ Wt2p,
                                             unsigned char* __restrict__ outp,
                                             const int* __restrict__ batch,
                                             float* __restrict__ gsum) {
    __shared__ __align__(16) unsigned char sm[MODE == 1 ? 20480 : 17024];
    int t = threadIdx.x;
    if (MODE == 1) {  // stage W2 into LDS once per block (swizzle per gemm2)
#pragma unroll
        for (int i = 0; i < 8; i++) {
            int id = t + i * 256;          // 2048 8-byte chunks
            int n = id >> 4, c = id & 15;
            *(uint2*)(sm + n * 128 + ((c ^ (n & 15)) << 3)) =
                *(const uint2*)(Wt2p + n * 128 + c * 8);
        }
        // first tile's __syncthreads covers this staging
    }
    int sub = t >> 4;
    int li = t & 15;
    unsigned lo8 = (unsigned)li * 8u;
    int wid = t >> 6, lane = t & 63;
    int par = 0;
    for (int tile = blockIdx.x; tile < NN / 16; tile += gridDim.x, par ^= 1) {
        int node = tile * 16 + sub;
        unsigned int md = meta[node];
        int base = (int)(md & 0x3FFFFFu);
        int degp = (int)(md >> 22);
        f32x2 A0 = {0.f, 0.f}, A1 = {0.f, 0.f}, A2 = {0.f, 0.f}, A3 = {0.f, 0.f};
#define LDH(idx) (*(const uint2*)(Hb + (unsigned)(idx) * 128u + lo8))
#define ACC8(V) { \
        A0 += f8_2f<0>((V).x); A1 += f8_2f<1>((V).x); \
        A2 += f8_2f<0>((V).y); A3 += f8_2f<1>((V).y); }
        uint2 v = LDH(node);  // self (already dinv-scaled)
        const int4* ip = (const int4*)(csr_src + base);
        int4 i0 = ip[0], i1 = ip[1], i2 = ip[2], i3 = ip[3];  // slack-safe
        ACC8(v)
        for (int e0 = 0; e0 < degp; e0 += 16) {
            // lower 8: always within padded segment (degp multiple of 8)
            uint2 w0 = LDH(i0.x), w1 = LDH(i0.y), w2 = LDH(i0.z), w3 = LDH(i0.w);
            uint2 w4 = LDH(i1.x), w5 = LDH(i1.y), w6 = LDH(i1.z), w7 = LDH(i1.w);
            uint2 w8 = {0, 0}, w9 = {0, 0}, wA = {0, 0}, wB = {0, 0};
            uint2 wC = {0, 0}, wD = {0, 0}, wE = {0, 0}, wF = {0, 0};
            if (e0 + 8 < degp) {  // sub-uniform
                w8 = LDH(i2.x); w9 = LDH(i2.y); wA = LDH(i2.z); wB = LDH(i2.w);
                wC = LDH(i3.x); wD = LDH(i3.y); wE = LDH(i3.z); wF = LDH(i3.w);
            }
            if (e0 + 16 < degp) {  // prefetch next index batch
                const int4* np = (const int4*)(csr_src + base + e0 + 16);
                i0 = np[0]; i1 = np[1]; i2 = np[2]; i3 = np[3];
            }
            ACC8(w0) ACC8(w1) ACC8(w2) ACC8(w3)
            ACC8(w4) ACC8(w5) ACC8(w6) ACC8(w7)
            ACC8(w8) ACC8(w9) ACC8(wA) ACC8(wB)
            ACC8(wC) ACC8(wD) ACC8(wE) ACC8(wF)
        }
#undef ACC8
#undef LDH
        float di = dinv[node];
        const float4* b4 = (const float4*)biasp;  // permuted bias
        float4 bA = b4[li * 2], bB = b4[li * 2 + 1];
        float r0 = fmaxf(fmaf(di, A0[0], bA.x), 0.f);
        float r1 = fmaxf(fmaf(di, A0[1], bA.y), 0.f);
        float r2 = fmaxf(fmaf(di, A1[0], bA.z), 0.f);
        float r3 = fmaxf(fmaf(di, A1[1], bA.w), 0.f);
        float r4 = fmaxf(fmaf(di, A2[0], bB.x), 0.f);
        float r5 = fmaxf(fmaf(di, A2[1], bB.y), 0.f);
        float r6 = fmaxf(fmaf(di, A3[0], bB.z), 0.f);
        float r7 = fmaxf(fmaf(di, A3[1], bB.w), 0.f);
        if (MODE == 2) {
            // ---- fused mean-pool path (double-buffered tile) ----
            float* buf = (float*)(sm + par * 8512);   // [16][132] padded
            int* gid = (int*)(sm + par * 8512 + 8448);
            int wb = sub * 132 + li * 8;
            buf[wb + 0] = r0; buf[wb + 1] = r1; buf[wb + 2] = r2; buf[wb + 3] = r3;
            buf[wb + 4] = r4; buf[wb + 5] = r5; buf[wb + 6] = r6; buf[wb + 7] = r7;
            if (li == 0) gid[sub] = batch[node];
            __syncthreads();
            if (t < 128) {  // column t: graph-segmented reduce over 16 rows
                int cg = gid[0];
                float s = buf[t];
#pragma unroll
                for (int r = 1; r < 16; r++) {
                    int g2 = gid[r];
                    if (g2 != cg) {
                        atomicAdd(&gsum[cg * 128 + t], s);
                        cg = g2; s = 0.f;
                    }
                    s += buf[r * 132 + t];
                }
                atomicAdd(&gsum[cg * 128 + t], s);
            }
        } else {
            unsigned int u0 = 0, u1 = 0;
            u0 = f2f8_lo(r0, r1, u0); u0 = f2f8_hi(r2, r3, u0);
            u1 = f2f8_lo(r4, r5, u1); u1 = f2f8_hi(r6, r7, u1);
            uint2 o; o.x = u0; o.y = u1;
            // ---- fused layer-2 GEMM path (waves 0,1 compute; 2,3 skip) ----
            unsigned char* At = sm + 16384 + par * 2048;  // A-tile dbuf
            *(uint2*)(At + sub * 128 + (((li ^ sub) & 15) << 3)) = o;
            __syncthreads();
            if (wid < 2) {
                int n16 = lane & 15, quad = lane >> 4;
                f32x4 acc[4];
#pragma unroll
                for (int j = 0; j < 4; j++) acc[j] = (f32x4){0.f, 0.f, 0.f, 0.f};
                int ct0 = wid * 4;
#pragma unroll
                for (int ks = 0; ks < 4; ks++) {
                    uint2 av = *(const uint2*)(At + n16 * 128 +
                                               ((((ks << 2) + quad) ^ n16) << 3));
                    long aa = __builtin_bit_cast(long, av);
#pragma unroll
                    for (int j = 0; j < 4; j++) {
                        uint2 bv = *(const uint2*)(sm + ((ct0 + j) * 16 + n16) * 128 +
                                                   ((((ks << 2) + quad) ^ n16) << 3));
                        long bb = __builtin_bit_cast(long, bv);
                        acc[j] = __builtin_amdgcn_mfma_f32_16x16x32_fp8_fp8(aa, bb, acc[j], 0, 0, 0);
                    }
                }
                // 4 results per (row,n16) are bytes ct0..ct0+3 of chunk n16
#pragma unroll
                for (int reg = 0; reg < 4; reg++) {
                    int row = tile * 16 + quad * 4 + reg;
                    float d2 = dinv[row];
                    unsigned int g = f2f8_lo(acc[0][reg] * d2, acc[1][reg] * d2, 0);
                    g = f2f8_hi(acc[2][reg] * d2, acc[3][reg] * d2, g);
                    *(unsigned int*)(outp + (size_t)row * 128 + n16 * 8 + ct0) = g;
                }
            }
        }
    }
}

// ------------------------------------------------- head MLP (pool precomputed)
// gsum[g][q]: per-graph f32 sums in permuted column order; counts from gstart.
__global__ __launch_bounds__(256) void k_head(const float* __restrict__ gsum,
                                              const int* __restrict__ gstart,
                                              const float* __restrict__ u,
                                              const float* __restrict__ Wh1,
                                              const float* __restrict__ bh1,
                                              const float* __restrict__ Wh2,
                                              const float* __restrict__ bh2,
                                              float* __restrict__ out) {
    int g = blockIdx.x, t = threadIdx.x;
    __shared__ float hc[192];
    __shared__ float tt[128];
    __shared__ float red[8];
    float cntf = (float)max(gstart[g + 1] - gstart[g], 1);
    if (t < 128) {
        int q = (t & 15) * 8 + (t >> 4);  // permuted position of col t
        hc[t] = gsum[g * 128 + q] / cntf;
    } else if (t < 192) {
        hc[t] = u[g * 64 + (t - 128)];
    }
    __syncthreads();
    if (t < 128) {
        float a2 = bh1[t];
#pragma unroll 8
        for (int k = 0; k < 192; k++) a2 = fmaf(hc[k], Wh1[k * 128 + t], a2);
        tt[t] = fmaxf(a2, 0.f);
    }
    __syncthreads();
    // final 128->2 layer: parallel products + shuffle-tree reduce
    int w = t >> 6;
    float p0 = 0.f, p1 = 0.f;
    if (t < 128) {
        float vv = tt[t];
        p0 = vv * Wh2[t * 2];
        p1 = vv * Wh2[t * 2 + 1];
    }
#pragma unroll
    for (int d = 32; d >= 1; d >>= 1) {
        p0 += __shfl_xor(p0, d);
        p1 += __shfl_xor(p1, d);
    }
    if ((t & 63) == 0) { red[w * 2] = p0; red[w * 2 + 1] = p1; }
    __syncthreads();
    if (t == 0) out[g * 2 + 0] = bh2[0] + red[0] + red[2];
    if (t == 1) out[g * 2 + 1] = bh2[1] + red[1] + red[3];
}

// ---------------------------------------------------------------- launcher
extern "C" void kernel_launch(void* const* d_in, const int* in_sizes, int n_in,
                              void* d_out, int out_size, void* d_ws, size_t ws_size,
                              hipStream_t stream) {
    const float* x   = (const float*)d_in[0];
    const int*   ei  = (const int*)d_in[1];
    const int*   row = ei;        // edge_index[0] = src
    const int*   col = ei + NE;   // edge_index[1] = dst
    const float* u   = (const float*)d_in[2];
    const int*   batch = (const int*)d_in[3];
    const float* W1  = (const float*)d_in[5];
    const float* b1  = (const float*)d_in[6];
    const float* W2  = (const float*)d_in[7];
    const float* b2  = (const float*)d_in[8];
    const float* Wh1 = (const float*)d_in[9];
    const float* bh1 = (const float*)d_in[10];
    const float* Wh2 = (const float*)d_in[11];
    const float* bh2 = (const float*)d_in[12];
    float* out = (float*)d_out;

    char* ws = (char*)d_ws;
    size_t o = 0;
    auto alloc = [&](size_t bytes) -> void* {
        void* p = ws + o;
        o += (bytes + 511) & ~(size_t)511;
        return p;
    };
    unsigned char*  Hs8 = (unsigned char*)alloc((size_t)(NN + 1) * 128); // L1 pre-gather (+dummy)
    unsigned char*  Hg2 = (unsigned char*)alloc((size_t)(NN + 1) * 128); // L2 pre-gather (+dummy)
    unsigned short* Wt1 = (unsigned short*)alloc((size_t)128 * 128 * 2);
    unsigned char*  Wt2p= (unsigned char*)alloc((size_t)128 * 128);
    float* b1p    = (float*)alloc((size_t)128 * 4);
    float* b2p    = (float*)alloc((size_t)128 * 4);
    float* dinv   = (float*)alloc((size_t)NN * 4);
    unsigned int* meta = (unsigned int*)alloc((size_t)NN * 4);
    int*   csr_src= (int*)alloc((size_t)NBK * SLOTC * 4 + 512);  // +slack for overread
    unsigned int* tmp = (unsigned int*)alloc((size_t)NBK * SLOT * 4);
    int*   gcur   = (int*)alloc((size_t)256 * 4);
    int*   gstart = (int*)alloc((size_t)(NG + 1) * 4);
    float* gsum   = (float*)alloc((size_t)NG * 128 * 4);

    // --- prep (W transforms + cursors + biases + graph starts + gsum=0) ---
    k_prep<<<645, 256, 0, stream>>>(W1, W2, b1, b2, Wt1, Wt2p, b1p, b2p, gcur,
                                    batch, gstart, Hs8, Hg2, gsum);
    k_bin2<<<400, 256, 0, stream>>>(row, col, gcur, tmp);
    k_bucket<<<NBK, 1024, 0, stream>>>(tmp, gcur, meta, dinv, csr_src);

    // --- layer 1 (f32 input, bf16 MFMA; fp8 H) ---
    k_gemm1<<<cdiv(NN, 128), 256, 0, stream>>>(x, Wt1, dinv, Hs8);
    // --- agg1 + layer-2 GEMM fused (persistent, 2-wave MFMA tail) ---
    k_agg<1><<<GAGG, 256, 0, stream>>>(Hs8, meta, csr_src, dinv, b1p, Wt2p,
                                       Hg2, nullptr, nullptr);
    // --- agg2 + mean-pool fused (persistent, f32 atomics into gsum) ---
    k_agg<2><<<GAGG, 256, 0, stream>>>(Hg2, meta, csr_src, dinv, b2p, nullptr,
                                       nullptr, batch, gsum);

    // --- head MLP ---
    k_head<<<NG, 256, 0, stream>>>(gsum, gstart, u, Wh1, bh1, Wh2, bh2, out);
}

// Round 11
// 226.002 us; speedup vs baseline: 1.0436x; 1.0436x over previous
//
#include <hip/hip_runtime.h>
#include <hip/hip_bf16.h>

#define NN 100000   // nodes
#define NE 1600000  // edges
#define NG 1000     // graphs
#define NBK 196     // dst buckets of 512 nodes (196*512 >= NN)
#define BSH 9       // bucket shift
#define SLOT 10240  // tmp slack region per bucket (mean 8192 + padding)
#define SLOTC 12288 // csr slack region per bucket (mean 8192 + 8-align pad ~3.5/node)

typedef short short8 __attribute__((ext_vector_type(8)));
typedef float f32x4 __attribute__((ext_vector_type(4)));
typedef float f32x2 __attribute__((ext_vector_type(2)));

static inline int cdiv(int a, int b) { return (a + b - 1) / b; }

// f32 -> bf16 (RNE) and helpers
__device__ __forceinline__ unsigned short f2b(float f) {
    unsigned int u = __float_as_uint(f);
    u += 0x7fff + ((u >> 16) & 1);
    return (unsigned short)(u >> 16);
}
__device__ __forceinline__ unsigned int pack2(float lo, float hi) {
    return (unsigned int)f2b(lo) | ((unsigned int)f2b(hi) << 16);
}

// fp8 e4m3 (OCP) hardware converts; word select must be an immediate constant
template <int W>
__device__ __forceinline__ f32x2 f8_2f(unsigned int v) {
    return __builtin_amdgcn_cvt_pk_f32_fp8((int)v, W);
}
__device__ __forceinline__ unsigned int f2f8_lo(float a, float b, unsigned int old) {
    return (unsigned int)__builtin_amdgcn_cvt_pk_fp8_f32(a, b, (int)old, false);
}
__device__ __forceinline__ unsigned int f2f8_hi(float a, float b, unsigned int old) {
    return (unsigned int)__builtin_amdgcn_cvt_pk_fp8_f32(a, b, (int)old, true);
}
__device__ __forceinline__ unsigned char f2f8s(float a) {
    return (unsigned char)(__builtin_amdgcn_cvt_pk_fp8_f32(a, a, 0, false) & 0xFF);
}

// ------------------------------------------------- prep
// Permuted byte order for fp8 rows: byte q holds col c(q) = (q&7)*16 + (q>>3).
// Wt1: bf16 [n][k] for layer-1 bf16 MFMA.
// Wt2p: fp8 [n][q] with k-rows permuted by the SAME c(q) as A1's byte order —
// joint k-permutation of A and B leaves the dot product invariant.
// Block 128 also zeroes row NN of BOTH gather buffers (dummy pad target).
// Blocks 129..519: scan sorted batch[] for graph start offsets.
// Blocks 520..644: zero gsum (per-graph f32 pool accumulators).
__global__ __launch_bounds__(256) void k_prep(const float* __restrict__ W1,
                                              const float* __restrict__ W2,
                                              const float* __restrict__ b1,
                                              const float* __restrict__ b2,
                                              unsigned short* __restrict__ Wt1,
                                              unsigned char* __restrict__ Wt2p,
                                              float* __restrict__ b1p,
                                              float* __restrict__ b2p,
                                              int* __restrict__ gcur,
                                              const int* __restrict__ batch,
                                              int* __restrict__ gstart,
                                              unsigned char* __restrict__ Hs8,
                                              unsigned char* __restrict__ Hg2,
                                              float* __restrict__ gsum) {
    int b = blockIdx.x, t = threadIdx.x;
    if (b < 128) {
        if (t < 128) {
            Wt1[b * 128 + t] = f2b(W1[t * 128 + b]);
        } else {
            int q = t - 128;
            int c = (q & 7) * 16 + (q >> 3);
            Wt2p[b * 128 + q] = f2f8s(W2[c * 128 + b]);
        }
    } else if (b == 128) {
        if (t < NBK) gcur[t] = t * SLOT;
        if (t < 128) {
            int c = (t & 7) * 16 + (t >> 3);  // col held at permuted position t
            b1p[t] = b1[c];
            b2p[t] = b2[c];
        }
        if (t >= 128 && t < 136) {
            uint4 z; z.x = 0u; z.y = 0u; z.z = 0u; z.w = 0u;
            ((uint4*)(Hs8 + (size_t)NN * 128))[t - 128] = z;  // zero dummy row L1
        }
        if (t >= 136 && t < 144) {
            uint4 z; z.x = 0u; z.y = 0u; z.z = 0u; z.w = 0u;
            ((uint4*)(Hg2 + (size_t)NN * 128))[t - 136] = z;  // zero dummy row L2
        }
    } else if (b < 520) {
        // graph boundary scan: n in [0, NN]; virtual batch[NN] = NG
        int n = (b - 129) * 256 + t;
        if (n <= NN) {
            int cur = (n == NN) ? NG : batch[n];
            int prev = (n == 0) ? -1 : batch[n - 1];
            for (int g = prev + 1; g <= cur; g++) gstart[g] = n;
        }
    } else {
        // zero gsum: NG*128 floats = 32000 uint4, 125 blocks x 256 threads
        int i = (b - 520) * 256 + t;
        if (i < NG * 32) {
            uint4 z; z.x = 0u; z.y = 0u; z.z = 0u; z.w = 0u;
            ((uint4*)gsum)[i] = z;
        }
    }
}

// -------------------------------------------------------- two-phase binning
// LDS counting-sort (R17-verified): entries sorted into bucket order in LDS,
// then written out linearly (coalesced).
__global__ __launch_bounds__(256) void k_bin2(const int* __restrict__ row,
                                              const int* __restrict__ col,
                                              int* __restrict__ gcur,
                                              unsigned int* __restrict__ tmp) {
    __shared__ unsigned int ent[4000];
    __shared__ unsigned int srt[4000];
    __shared__ unsigned char bkt[4000];
    __shared__ unsigned char bky[4000];
    __shared__ int cnt[NBK];
    __shared__ int gbase[NBK];
    __shared__ int lbase[NBK];
    __shared__ int sh[256];
    int t = threadIdx.x;
    if (t < NBK) cnt[t] = 0;
    __syncthreads();
    const int q0 = blockIdx.x * 1000;  // int4 index base (4000 edges)
    const int4* col4 = (const int4*)col;
    const int4* row4 = (const int4*)row;
#pragma unroll
    for (int it = 0; it < 4; it++) {
        int idx = it * 256 + t;
        if (idx < 1000) {
            int4 c = col4[q0 + idx];
            int4 r = row4[q0 + idx];
            int d, b;
            d = c.x; b = d >> BSH; atomicAdd(&cnt[b], 1);
            ent[idx * 4 + 0] = ((unsigned int)(d & 511) << 17) | (unsigned int)r.x;
            bkt[idx * 4 + 0] = (unsigned char)b;
            d = c.y; b = d >> BSH; atomicAdd(&cnt[b], 1);
            ent[idx * 4 + 1] = ((unsigned int)(d & 511) << 17) | (unsigned int)r.y;
            bkt[idx * 4 + 1] = (unsigned char)b;
            d = c.z; b = d >> BSH; atomicAdd(&cnt[b], 1);
            ent[idx * 4 + 2] = ((unsigned int)(d & 511) << 17) | (unsigned int)r.z;
            bkt[idx * 4 + 2] = (unsigned char)b;
            d = c.w; b = d >> BSH; atomicAdd(&cnt[b], 1);
            ent[idx * 4 + 3] = ((unsigned int)(d & 511) << 17) | (unsigned int)r.w;
            bkt[idx * 4 + 3] = (unsigned char)b;
        }
    }
    __syncthreads();
    int v = (t < NBK) ? cnt[t] : 0;
    sh[t] = v;
    __syncthreads();
    for (int d = 1; d < 256; d <<= 1) {
        int u = (t >= d) ? sh[t - d] : 0;
        __syncthreads();
        sh[t] += u;
        __syncthreads();
    }
    if (t < NBK) {
        lbase[t] = sh[t] - v;
        gbase[t] = atomicAdd(&gcur[t], v);
        cnt[t] = sh[t] - v;  // becomes local cursor
    }
    __syncthreads();
#pragma unroll
    for (int it = 0; it < 16; it++) {
        int i = it * 256 + t;
        if (i < 4000) {
            int b = bkt[i];
            int p = atomicAdd(&cnt[b], 1);
            srt[p] = ent[i];
            bky[p] = (unsigned char)b;
        }
    }
    __syncthreads();
#pragma unroll
    for (int it = 0; it < 16; it++) {
        int i = it * 256 + t;
        if (i < 4000) {
            int b = bky[i];
            tmp[gbase[b] + (i - lbase[b])] = srt[i];
        }
    }
}

// -------------------------------------------------------- per-bucket CSR
// Segments padded to 8-entry alignment; pad entries filled with dummy index NN
// (points at the zeroed row of the gather buffer) so aggregation gathers
// unconditionally. meta[node] = csr_offset | (padded_degree << 22).
// Entries stashed in LDS during the count pass (no tmp re-read).
__global__ __launch_bounds__(1024) void k_bucket(const unsigned int* __restrict__ tmp,
                                                 const int* __restrict__ gcur,
                                                 unsigned int* __restrict__ meta,
                                                 float* __restrict__ dinv,
                                                 int* __restrict__ csr_src) {
    __shared__ unsigned int sent[SLOT];  // 40 KB entry stash
    __shared__ int cnt[512];
    __shared__ int loff[512];
    __shared__ int send[512];
    __shared__ int sh[256];
    int b = blockIdx.x, t = threadIdx.x;
    int j0 = b << BSH;
    int nd = min(512, NN - j0);
    int rb = b * SLOT;     // tmp base
    int rbc = b * SLOTC;   // csr base
    int m = gcur[b] - rb;
    if (t < 512) cnt[t] = 0;
    __syncthreads();
    for (int i = t; i < m; i += 1024) {
        unsigned int e = tmp[rb + i];
        sent[i] = e;
        atomicAdd(&cnt[e >> 17], 1);
    }
    __syncthreads();
    int r0 = 0, r1 = 0, p0 = 0, ts = 0;
    if (t < 256) {
        r0 = cnt[2 * t]; r1 = cnt[2 * t + 1];
        p0 = (r0 + 7) & ~7;
        int p1 = (r1 + 7) & ~7;  // pad to 8-entry alignment
        ts = p0 + p1;
        sh[t] = ts;
    }
    __syncthreads();
    for (int d = 1; d < 256; d <<= 1) {
        int u = (t >= d && t < 256) ? sh[t - d] : 0;
        __syncthreads();
        if (t < 256) sh[t] += u;
        __syncthreads();
    }
    if (t < 256) {
        int ex = sh[t] - ts;
        loff[2 * t] = ex;
        loff[2 * t + 1] = ex + p0;
    }
    __syncthreads();
    for (int j = t; j < nd; j += 1024) {
        int o = rbc + loff[j];
        int dg = cnt[j];
        int dgp = (dg + 7) & ~7;
        meta[j0 + j] = (unsigned int)o | ((unsigned int)dgp << 22);
        send[j] = o + dgp;
        dinv[j0 + j] = rsqrtf((float)(dg + 1));  // +1 self-loop
        cnt[j] = o;  // becomes cursor
    }
    __syncthreads();
    for (int i = t; i < m; i += 1024) {
        unsigned int e = sent[i];
        int d = e >> 17;
        int s = (int)(e & 0x1FFFFu);
        int p = atomicAdd(&cnt[d], 1);
        csr_src[p] = s;
    }
    __syncthreads();
    for (int j = t; j < nd; j += 1024) {
        int pe = send[j];
        for (int p = cnt[j]; p < pe; p++) csr_src[p] = NN;  // dummy (zero row)
    }
}

// ---------------------------------------------------------------- GEMM layer 1
// Hs8[r] = fp8( dinv[r] * (bf16(x) @ Wt1^T) row r ), PERMUTED bytes (q=n16*8+ct).
__global__ __launch_bounds__(256) void k_gemm1(const float* __restrict__ X,
                                               const unsigned short* __restrict__ Wt,
                                               const float* __restrict__ dinv,
                                               unsigned char* __restrict__ Hs8) {
    __shared__ __align__(16) unsigned short Ws[128 * 128];  // 32 KB
    int t = threadIdx.x;
#pragma unroll
    for (int i = 0; i < 8; i++) {
        int id = t + i * 256;
        int n = id >> 4, c = id & 15;
        *(short8*)((char*)Ws + n * 256 + ((c ^ (n & 15)) << 4)) =
            *(const short8*)(Wt + n * 128 + c * 8);
    }
    __syncthreads();

    int lane = t & 63, wid = t >> 6;
    int n16 = lane & 15, quad = lane >> 4;
    int row_base = blockIdx.x * 128 + wid * 32;

    short8 a[2][4];
#pragma unroll
    for (int rt = 0; rt < 2; rt++) {
        int r = row_base + rt * 16 + n16;
        if (r > NN - 1) r = NN - 1;
        const float* ap = X + (size_t)r * 128 + quad * 8;
#pragma unroll
        for (int ks = 0; ks < 4; ks++) {
            float4 v0 = *(const float4*)(ap + ks * 32);
            float4 v1 = *(const float4*)(ap + ks * 32 + 4);
            uint4 up;
            up.x = pack2(v0.x, v0.y); up.y = pack2(v0.z, v0.w);
            up.z = pack2(v1.x, v1.y); up.w = pack2(v1.z, v1.w);
            a[rt][ks] = *(short8*)&up;
        }
    }

    f32x4 acc[2][8];
#pragma unroll
    for (int rt = 0; rt < 2; rt++)
#pragma unroll
        for (int ct = 0; ct < 8; ct++)
            acc[rt][ct] = (f32x4){0.f, 0.f, 0.f, 0.f};

#pragma unroll
    for (int ks = 0; ks < 4; ks++) {
#pragma unroll
        for (int ct = 0; ct < 8; ct++) {
            short8 b = *(const short8*)((const char*)Ws +
                        (ct * 16 + n16) * 256 + ((((ks << 2) + quad) ^ n16) << 4));
            acc[0][ct] = __builtin_amdgcn_mfma_f32_16x16x32_bf16(a[0][ks], b, acc[0][ct], 0, 0, 0);
            acc[1][ct] = __builtin_amdgcn_mfma_f32_16x16x32_bf16(a[1][ks], b, acc[1][ct], 0, 0, 0);
        }
    }

#pragma unroll
    for (int rt = 0; rt < 2; rt++) {
#pragma unroll
        for (int reg = 0; reg < 4; reg++) {
            int row = row_base + rt * 16 + quad * 4 + reg;
            if (row < NN) {
                float di = dinv[row];
                unsigned int u0 = 0, u1 = 0;
                u0 = f2f8_lo(acc[rt][0][reg] * di, acc[rt][1][reg] * di, u0);
                u0 = f2f8_hi(acc[rt][2][reg] * di, acc[rt][3][reg] * di, u0);
                u1 = f2f8_lo(acc[rt][4][reg] * di, acc[rt][5][reg] * di, u1);
                u1 = f2f8_hi(acc[rt][6][reg] * di, acc[rt][7][reg] * di, u1);
                uint2 o; o.x = u0; o.y = u1;
                ((uint2*)(Hs8 + (size_t)row * 128))[n16] = o;
            }
        }
    }
}

// ------------------------------------------- aggregation (+fused tails)
// out[i] = relu( dinv[i] * (Hs[i] + sum_e Hs[src_e]) + bias ), fp8 permuted.
// Sub-owns-node (16 lanes/node, 4 nodes/wave — R4-verified low-VGPR shape),
// deep-pipelined: 16 edges/iter, 16 gathers in flight, index prefetch. CSR is
// 8-padded with dummy index NN (zero row): lower 8 gathers unconditional.
// MODE=1 (layer 1, R8-verified): W2 staged in 16KB LDS at kernel start
// (overlaps the latency-bound gather), A-tile staged in 2KB LDS; after one
// barrier, WAVES 0 AND 1 run the fp8 MFMA (wave w: column-tiles w*4..w*4+3).
// Byte position within each 8B chunk == ct, so wave0's 4 results form the low
// dword and wave1's the high dword -> direct dword global stores, no recombine.
// MODE=2 (layer 2 + fused mean-pool): instead of packing/storing fp8, the
// post-relu f32 values go to a [16][132] LDS tile; after one barrier, threads
// 0..127 run a graph-segmented column reduce over the block's 16 consecutive
// nodes and atomicAdd per-graph partial sums into gsum[NG][128] (f32, permuted
// column order). batch[] sorted -> most blocks touch 1 graph (~1 atomic/col).
template <int MODE>
__global__ __launch_bounds__(256) void k_agg(const unsigned char* __restrict__ Hb,
                                             const unsigned int* __restrict__ meta,
                                             const int* __restrict__ csr_src,
                                             const float* __restrict__ dinv,
                                             const float* __restrict__ biasp,
                                             const unsigned char* __restrict__ Wt2p,
                                             unsigned char* __restrict__ outp,
                                             const int* __restrict__ batch,
                                             float* __restrict__ gsum) {
    __shared__ __align__(16) unsigned char sm[MODE == 1 ? 18432 : 8512];
    int t = threadIdx.x;
    if (MODE == 1) {  // stage W2 into LDS (same swizzle as verified gemm2)
#pragma unroll
        for (int i = 0; i < 8; i++) {
            int id = t + i * 256;          // 2048 8-byte chunks
            int n = id >> 4, c = id & 15;
            *(uint2*)(sm + n * 128 + ((c ^ (n & 15)) << 3)) =
                *(const uint2*)(Wt2p + n * 128 + c * 8);
        }
    }
    int sub = t >> 4;
    int node = blockIdx.x * 16 + sub;  // grid = NN/16 = 6250 exact
    int li = t & 15;
    unsigned lo8 = (unsigned)li * 8u;
    unsigned int md = meta[node];
    int base = (int)(md & 0x3FFFFFu);
    int degp = (int)(md >> 22);
    f32x2 A0 = {0.f, 0.f}, A1 = {0.f, 0.f}, A2 = {0.f, 0.f}, A3 = {0.f, 0.f};
#define LDH(idx) (*(const uint2*)(Hb + (unsigned)(idx) * 128u + lo8))
#define ACC8(V) { \
        A0 += f8_2f<0>((V).x); A1 += f8_2f<1>((V).x); \
        A2 += f8_2f<0>((V).y); A3 += f8_2f<1>((V).y); }
    uint2 v = LDH(node);  // self (already dinv-scaled)
    const int4* ip = (const int4*)(csr_src + base);
    int4 i0 = ip[0], i1 = ip[1], i2 = ip[2], i3 = ip[3];  // slack-safe overread
    ACC8(v)
    for (int e0 = 0; e0 < degp; e0 += 16) {
        // lower 8: always within padded segment (degp is a multiple of 8)
        uint2 w0 = LDH(i0.x), w1 = LDH(i0.y), w2 = LDH(i0.z), w3 = LDH(i0.w);
        uint2 w4 = LDH(i1.x), w5 = LDH(i1.y), w6 = LDH(i1.z), w7 = LDH(i1.w);
        uint2 w8 = {0, 0}, w9 = {0, 0}, wA = {0, 0}, wB = {0, 0};
        uint2 wC = {0, 0}, wD = {0, 0}, wE = {0, 0}, wF = {0, 0};
        if (e0 + 8 < degp) {  // sub-uniform
            w8 = LDH(i2.x); w9 = LDH(i2.y); wA = LDH(i2.z); wB = LDH(i2.w);
            wC = LDH(i3.x); wD = LDH(i3.y); wE = LDH(i3.z); wF = LDH(i3.w);
        }
        if (e0 + 16 < degp) {  // prefetch next index batch during accumulate
            const int4* np = (const int4*)(csr_src + base + e0 + 16);
            i0 = np[0]; i1 = np[1]; i2 = np[2]; i3 = np[3];
        }
        ACC8(w0) ACC8(w1) ACC8(w2) ACC8(w3)
        ACC8(w4) ACC8(w5) ACC8(w6) ACC8(w7)
        ACC8(w8) ACC8(w9) ACC8(wA) ACC8(wB)
        ACC8(wC) ACC8(wD) ACC8(wE) ACC8(wF)
    }
#undef ACC8
#undef LDH
    float di = dinv[node];
    const float4* b4 = (const float4*)biasp;  // permuted bias
    float4 bA = b4[li * 2], bB = b4[li * 2 + 1];
    float r0 = fmaxf(fmaf(di, A0[0], bA.x), 0.f);
    float r1 = fmaxf(fmaf(di, A0[1], bA.y), 0.f);
    float r2 = fmaxf(fmaf(di, A1[0], bA.z), 0.f);
    float r3 = fmaxf(fmaf(di, A1[1], bA.w), 0.f);
    float r4 = fmaxf(fmaf(di, A2[0], bB.x), 0.f);
    float r5 = fmaxf(fmaf(di, A2[1], bB.y), 0.f);
    float r6 = fmaxf(fmaf(di, A3[0], bB.z), 0.f);
    float r7 = fmaxf(fmaf(di, A3[1], bB.w), 0.f);
    if (MODE == 2) {
        // ---- fused mean-pool path ----
        float* buf = (float*)sm;                 // [16][132] (pad kills conflicts)
        int* gid = (int*)(sm + 8448);            // [16] graph ids
        int wb = sub * 132 + li * 8;
        buf[wb + 0] = r0; buf[wb + 1] = r1; buf[wb + 2] = r2; buf[wb + 3] = r3;
        buf[wb + 4] = r4; buf[wb + 5] = r5; buf[wb + 6] = r6; buf[wb + 7] = r7;
        if (li == 0) gid[sub] = batch[node];
        __syncthreads();
        if (t < 128) {  // column t: graph-segmented reduce over 16 rows
            int cg = gid[0];
            float s = buf[t];
#pragma unroll
            for (int r = 1; r < 16; r++) {
                int g2 = gid[r];
                if (g2 != cg) {
                    atomicAdd(&gsum[cg * 128 + t], s);
                    cg = g2; s = 0.f;
                }
                s += buf[r * 132 + t];
            }
            atomicAdd(&gsum[cg * 128 + t], s);
        }
        return;
    }
    unsigned int u0 = 0, u1 = 0;
    u0 = f2f8_lo(r0, r1, u0); u0 = f2f8_hi(r2, r3, u0);
    u1 = f2f8_lo(r4, r5, u1); u1 = f2f8_hi(r6, r7, u1);
    uint2 o; o.x = u0; o.y = u1;
    // ---- fused layer-2 GEMM path (waves 0 and 1; waves 2-3 retire) ----
    // A-tile: row = sub, 8B chunk li at XOR-swizzled slot (bijective per row)
    *(uint2*)(sm + 16384 + sub * 128 + (((li ^ sub) & 15) << 3)) = o;
    __syncthreads();
    int wid = t >> 6, lane = t & 63;
    if (wid < 2) {
        int n16 = lane & 15, quad = lane >> 4;
        f32x4 acc[4];
#pragma unroll
        for (int j = 0; j < 4; j++) acc[j] = (f32x4){0.f, 0.f, 0.f, 0.f};
        int ct0 = wid * 4;
#pragma unroll
        for (int ks = 0; ks < 4; ks++) {
            uint2 av = *(const uint2*)(sm + 16384 + n16 * 128 +
                                       ((((ks << 2) + quad) ^ n16) << 3));
            long aa = __builtin_bit_cast(long, av);
#pragma unroll
            for (int j = 0; j < 4; j++) {
                uint2 bv = *(const uint2*)(sm + ((ct0 + j) * 16 + n16) * 128 +
                                           ((((ks << 2) + quad) ^ n16) << 3));
                long bb = __builtin_bit_cast(long, bv);
                acc[j] = __builtin_amdgcn_mfma_f32_16x16x32_fp8_fp8(aa, bb, acc[j], 0, 0, 0);
            }
        }
        // wave w's 4 results per (row, n16) are bytes ct0..ct0+3 of chunk n16
        // -> one dword at offset n16*8 + ct0 (wave0 low dword, wave1 high)
#pragma unroll
        for (int reg = 0; reg < 4; reg++) {
            int row = blockIdx.x * 16 + quad * 4 + reg;
            float d2 = dinv[row];
            unsigned int g = f2f8_lo(acc[0][reg] * d2, acc[1][reg] * d2, 0);
            g = f2f8_hi(acc[2][reg] * d2, acc[3][reg] * d2, g);
            *(unsigned int*)(outp + (size_t)row * 128 + n16 * 8 + ct0) = g;
        }
    }
}

// ------------------------------------------------- head MLP (pool precomputed)
// gsum[g][q]: per-graph f32 sums in permuted column order; counts from gstart.
__global__ __launch_bounds__(256) void k_head(const float* __restrict__ gsum,
                                              const int* __restrict__ gstart,
                                              const float* __restrict__ u,
                                              const float* __restrict__ Wh1,
                                              const float* __restrict__ bh1,
                                              const float* __restrict__ Wh2,
                                              const float* __restrict__ bh2,
                                              float* __restrict__ out) {
    int g = blockIdx.x, t = threadIdx.x;
    __shared__ float hc[192];
    __shared__ float tt[128];
    __shared__ float red[8];
    float cntf = (float)max(gstart[g + 1] - gstart[g], 1);
    if (t < 128) {
        int q = (t & 15) * 8 + (t >> 4);  // permuted position of col t
        hc[t] = gsum[g * 128 + q] / cntf;
    } else if (t < 192) {
        hc[t] = u[g * 64 + (t - 128)];
    }
    __syncthreads();
    if (t < 128) {
        float a2 = bh1[t];
#pragma unroll 8
        for (int k = 0; k < 192; k++) a2 = fmaf(hc[k], Wh1[k * 128 + t], a2);
        tt[t] = fmaxf(a2, 0.f);
    }
    __syncthreads();
    // final 128->2 layer: parallel products + shuffle-tree reduce
    int w = t >> 6;
    float p0 = 0.f, p1 = 0.f;
    if (t < 128) {
        float vv = tt[t];
        p0 = vv * Wh2[t * 2];
        p1 = vv * Wh2[t * 2 + 1];
    }
#pragma unroll
    for (int d = 32; d >= 1; d >>= 1) {
        p0 += __shfl_xor(p0, d);
        p1 += __shfl_xor(p1, d);
    }
    if ((t & 63) == 0) { red[w * 2] = p0; red[w * 2 + 1] = p1; }
    __syncthreads();
    if (t == 0) out[g * 2 + 0] = bh2[0] + red[0] + red[2];
    if (t == 1) out[g * 2 + 1] = bh2[1] + red[1] + red[3];
}

// ---------------------------------------------------------------- launcher
extern "C" void kernel_launch(void* const* d_in, const int* in_sizes, int n_in,
                              void* d_out, int out_size, void* d_ws, size_t ws_size,
                              hipStream_t stream) {
    const float* x   = (const float*)d_in[0];
    const int*   ei  = (const int*)d_in[1];
    const int*   row = ei;        // edge_index[0] = src
    const int*   col = ei + NE;   // edge_index[1] = dst
    const float* u   = (const float*)d_in[2];
    const int*   batch = (const int*)d_in[3];
    const float* W1  = (const float*)d_in[5];
    const float* b1  = (const float*)d_in[6];
    const float* W2  = (const float*)d_in[7];
    const float* b2  = (const float*)d_in[8];
    const float* Wh1 = (const float*)d_in[9];
    const float* bh1 = (const float*)d_in[10];
    const float* Wh2 = (const float*)d_in[11];
    const float* bh2 = (const float*)d_in[12];
    float* out = (float*)d_out;

    char* ws = (char*)d_ws;
    size_t o = 0;
    auto alloc = [&](size_t bytes) -> void* {
        void* p = ws + o;
        o += (bytes + 511) & ~(size_t)511;
        return p;
    };
    unsigned char*  Hs8 = (unsigned char*)alloc((size_t)(NN + 1) * 128); // L1 pre-gather (+dummy)
    unsigned char*  Hg2 = (unsigned char*)alloc((size_t)(NN + 1) * 128); // L2 pre-gather (+dummy)
    unsigned short* Wt1 = (unsigned short*)alloc((size_t)128 * 128 * 2);
    unsigned char*  Wt2p= (unsigned char*)alloc((size_t)128 * 128);
    float* b1p    = (float*)alloc((size_t)128 * 4);
    float* b2p    = (float*)alloc((size_t)128 * 4);
    float* dinv   = (float*)alloc((size_t)NN * 4);
    unsigned int* meta = (unsigned int*)alloc((size_t)NN * 4);
    int*   csr_src= (int*)alloc((size_t)NBK * SLOTC * 4 + 512);  // +slack for overread
    unsigned int* tmp = (unsigned int*)alloc((size_t)NBK * SLOT * 4);
    int*   gcur   = (int*)alloc((size_t)256 * 4);
    int*   gstart = (int*)alloc((size_t)(NG + 1) * 4);
    float* gsum   = (float*)alloc((size_t)NG * 128 * 4);

    // --- prep (W transforms + cursors + biases + graph starts + gsum=0) ---
    k_prep<<<645, 256, 0, stream>>>(W1, W2, b1, b2, Wt1, Wt2p, b1p, b2p, gcur,
                                    batch, gstart, Hs8, Hg2, gsum);
    k_bin2<<<400, 256, 0, stream>>>(row, col, gcur, tmp);
    k_bucket<<<NBK, 1024, 0, stream>>>(tmp, gcur, meta, dinv, csr_src);

    // --- layer 1 (f32 input, bf16 MFMA; fp8 H) ---
    k_gemm1<<<cdiv(NN, 128), 256, 0, stream>>>(x, Wt1, dinv, Hs8);
    // --- agg1 + layer-2 GEMM fused (2-wave MFMA tail, dword stores) ---
    k_agg<1><<<NN / 16, 256, 0, stream>>>(Hs8, meta, csr_src, dinv, b1p, Wt2p,
                                          Hg2, nullptr, nullptr);
    // --- agg2 + mean-pool fused (f32 atomics into gsum) ---
    k_agg<2><<<NN / 16, 256, 0, stream>>>(Hg2, meta, csr_src, dinv, b2p, nullptr,
                                          nullptr, batch, gsum);

    // --- head MLP ---
    k_head<<<NG, 256, 0, stream>>>(gsum, gstart, u, Wh1, bh1, Wh2, bh2, out);
}